// Round 3
// baseline (628.206 us; speedup 1.0000x reference)
//
#include <hip/hip_runtime.h>
#include <hip/hip_bf16.h>

// MoE layer, routed top-2. f16 MFMA (fp32 accumulate), fp64 gating.
// Round 3: software-pipelined K-loop (double-buffered LDS, DMA tile k+1
// issued before waiting tile k, s_waitcnt vmcnt(N!=0) + raw s_barrier),
// mm2 retiled to 128x64 for 2x grid parallelism.

#define N_TOK 4096
#define DIM   768
#define FDIM  3072
#define NEXP  8

typedef __attribute__((ext_vector_type(8))) _Float16 f16x8;
typedef __attribute__((ext_vector_type(4))) _Float16 f16x4;
typedef __attribute__((ext_vector_type(4))) float     f32x4;

__device__ __forceinline__ float gelu_exact(float v) {
    return 0.5f * v * (1.0f + erff(v * 0.7071067811865475f));
}

// async 16B/lane global->LDS DMA; lds dest = wave-uniform base + lane*16
__device__ __forceinline__ void gl_lds16(const _Float16* g, _Float16* l) {
    __builtin_amdgcn_global_load_lds(
        (const __attribute__((address_space(1))) unsigned int*)g,
        (__attribute__((address_space(3))) unsigned int*)l, 16, 0, 0);
}

// ---------------- cast x (fp32 -> f16), vectorized ----------------
__global__ __launch_bounds__(256) void cast_x_kernel(const float* __restrict__ x,
                                                     _Float16* __restrict__ xh) {
    int i = blockIdx.x * 256 + threadIdx.x;
    float4 v = ((const float4*)x)[i];
    f16x4 o;
    o[0] = (_Float16)v.x; o[1] = (_Float16)v.y;
    o[2] = (_Float16)v.z; o[3] = (_Float16)v.w;
    ((f16x4*)xh)[i] = o;
}

// ---------------- transpose + cast: fp32 [E][R][C] -> f16 [E][C][R] ----------------
__global__ __launch_bounds__(256) void transpose_cast_kernel(const float* __restrict__ in,
                                                             _Float16* __restrict__ out,
                                                             int R, int C) {
    const int e  = blockIdx.z;
    const size_t eoff = (size_t)e * R * C;
    const int c0 = blockIdx.x * 64;
    const int r0 = blockIdx.y * 64;
    __shared__ _Float16 tile[64][66];
    const int t = threadIdx.x;
    #pragma unroll
    for (int it = 0; it < 4; it++) {
        int lin = it * 256 + t;
        int r  = lin >> 4;
        int c4 = lin & 15;
        float4 v = *(const float4*)&in[eoff + (size_t)(r0 + r) * C + c0 + c4 * 4];
        tile[r][c4 * 4 + 0] = (_Float16)v.x;
        tile[r][c4 * 4 + 1] = (_Float16)v.y;
        tile[r][c4 * 4 + 2] = (_Float16)v.z;
        tile[r][c4 * 4 + 3] = (_Float16)v.w;
    }
    __syncthreads();
    #pragma unroll
    for (int it = 0; it < 4; it++) {
        int lin = it * 256 + t;
        int c  = lin >> 4;
        int r4 = lin & 15;
        f16x4 o;
        #pragma unroll
        for (int j = 0; j < 4; j++) o[j] = tile[r4 * 4 + j][c];
        *(f16x4*)&out[eoff + (size_t)(c0 + c) * R + r0 + r4 * 4] = o;
    }
}

// ---------------- gating: fp64 logits, softmax, top-2, per-expert lists ----------------
__global__ __launch_bounds__(256) void gate_kernel(const float* __restrict__ x,
                                                   const float* __restrict__ gw,
                                                   const float* __restrict__ gb,
                                                   int* __restrict__ tok_list,
                                                   float* __restrict__ wt_list,
                                                   int* __restrict__ count) {
    const int gtid = blockIdx.x * 256 + threadIdx.x;
    const int n    = gtid >> 6;
    const int lane = threadIdx.x & 63;
    if (n >= N_TOK) return;
    double part[NEXP];
    #pragma unroll
    for (int e = 0; e < NEXP; e++) part[e] = 0.0;
    for (int d = lane; d < DIM; d += 64) {
        float xv = x[n * DIM + d];
        const float* g = &gw[d * NEXP];
        #pragma unroll
        for (int e = 0; e < NEXP; e++) part[e] += (double)xv * (double)g[e];
    }
    #pragma unroll
    for (int e = 0; e < NEXP; e++) {
        double v = part[e];
        #pragma unroll
        for (int off = 32; off > 0; off >>= 1) v += __shfl_xor(v, off);
        part[e] = v + (double)gb[e];
    }
    if (lane == 0) {
        double mx = part[0];
        #pragma unroll
        for (int e = 1; e < NEXP; e++) mx = fmax(mx, part[e]);
        double ex[NEXP]; double s = 0.0;
        #pragma unroll
        for (int e = 0; e < NEXP; e++) { ex[e] = exp(part[e] - mx); s += ex[e]; }
        int i0 = 0;
        #pragma unroll
        for (int e = 1; e < NEXP; e++) if (ex[e] > ex[i0]) i0 = e;
        int i1 = (i0 == 0) ? 1 : 0;
        #pragma unroll
        for (int e = 0; e < NEXP; e++) if (e != i0 && ex[e] > ex[i1]) i1 = e;
        float g0 = (float)(ex[i0] / s), g1 = (float)(ex[i1] / s);
        float dn = g0 + g1 + 1e-9f;
        float w0 = g0 / dn, w1 = g1 / dn;
        int s0 = atomicAdd(&count[i0], 1);
        tok_list[i0 * N_TOK + s0] = n;  wt_list[i0 * N_TOK + s0] = w0;
        int s1 = atomicAdd(&count[i1], 1);
        tok_list[i1 * N_TOK + s1] = n;  wt_list[i1 * N_TOK + s1] = w1;
    }
}

// ---------------- tiny prefix scan over 8 expert counts ----------------
__global__ void scan_kernel(const int* __restrict__ count, int* __restrict__ basep) {
    if (threadIdx.x == 0) {
        int s = 0;
        for (int e = 0; e < NEXP; e++) { basep[e] = s; s += count[e]; }
    }
}

// ================= GEMM1: h = gelu(x_gathered @ w1[e] + b1[e]) =================
// 128x128 tile, BK=32, pipelined double-buffer. Fragment-order LDS:
// [m-block(16 rows)][quad][m][8] -> frag read = base + lane*8, 0 conflicts,
// and matches the DMA's (uniform base + lane*16) write pattern.
__global__ __launch_bounds__(256) void mm1_kernel(const _Float16* __restrict__ xh,
                                                  const _Float16* __restrict__ w1t,
                                                  const float* __restrict__ bias1,
                                                  const int* __restrict__ tok_list,
                                                  const int* __restrict__ count,
                                                  const int* __restrict__ basep,
                                                  _Float16* __restrict__ h) {
    const int e    = blockIdx.z;
    const int cnt  = count[e];
    const int row0 = blockIdx.y * 128;
    if (row0 >= cnt) return;
    const int col0 = blockIdx.x * 128;
    const int t    = threadIdx.x;
    const int lane = t & 63;
    const int wv   = t >> 6;
    const int wy   = wv >> 1, wx = wv & 1;
    const int m_lane = lane & 15, quad = lane >> 4;

    __shared__ __align__(16) _Float16 As[2][4096];   // 8 blocks x 512 per buffer
    __shared__ __align__(16) _Float16 Bs[2][4096];

    const int b0 = wv * 2, b1 = b0 + 1;
    int ra0 = row0 + b0 * 16 + m_lane; if (ra0 > cnt - 1) ra0 = cnt - 1;
    int ra1 = row0 + b1 * 16 + m_lane; if (ra1 > cnt - 1) ra1 = cnt - 1;
    const int tokA0 = tok_list[e * N_TOK + ra0];
    const int tokA1 = tok_list[e * N_TOK + ra1];
    const _Float16* pa0 = xh + (size_t)tokA0 * DIM + quad * 8;
    const _Float16* pa1 = xh + (size_t)tokA1 * DIM + quad * 8;
    const _Float16* pb0 = w1t + (size_t)e * FDIM * DIM
                        + (size_t)(col0 + b0 * 16 + m_lane) * DIM + quad * 8;
    const _Float16* pb1 = pb0 + (size_t)16 * DIM;

    f32x4 acc[4][4];
    #pragma unroll
    for (int i = 0; i < 4; i++)
        #pragma unroll
        for (int j = 0; j < 4; j++)
            acc[i][j] = (f32x4){0.f, 0.f, 0.f, 0.f};

    auto compute = [&](int cur) {
        f16x8 af[4], bf[4];
        #pragma unroll
        for (int i = 0; i < 4; i++)
            af[i] = *(const f16x8*)&As[cur][(wy * 4 + i) * 512 + lane * 8];
        #pragma unroll
        for (int j = 0; j < 4; j++)
            bf[j] = *(const f16x8*)&Bs[cur][(wx * 4 + j) * 512 + lane * 8];
        #pragma unroll
        for (int i = 0; i < 4; i++)
            #pragma unroll
            for (int j = 0; j < 4; j++)
                acc[i][j] = __builtin_amdgcn_mfma_f32_16x16x32_f16(af[i], bf[j], acc[i][j], 0, 0, 0);
    };

    const int NK = DIM / 32;   // 24
    // prologue: tile 0 -> buf 0
    gl_lds16(pa0, &As[0][b0 * 512]);
    gl_lds16(pa1, &As[0][b1 * 512]);
    gl_lds16(pb0, &Bs[0][b0 * 512]);
    gl_lds16(pb1, &Bs[0][b1 * 512]);

    for (int k = 0; k < NK - 1; k++) {
        const int cur = k & 1, nxt = cur ^ 1;
        const int off = (k + 1) * 32;
        // issue tile k+1 into nxt (last read at iter k-1; end barrier freed it)
        gl_lds16(pa0 + off, &As[nxt][b0 * 512]);
        gl_lds16(pa1 + off, &As[nxt][b1 * 512]);
        gl_lds16(pb0 + off, &Bs[nxt][b0 * 512]);
        gl_lds16(pb1 + off, &Bs[nxt][b1 * 512]);
        asm volatile("s_waitcnt vmcnt(4)" ::: "memory");   // tile k arrived, k+1 in flight
        __builtin_amdgcn_s_barrier();
        compute(cur);
        __builtin_amdgcn_s_barrier();                      // protect nxt for reuse
    }
    asm volatile("s_waitcnt vmcnt(0)" ::: "memory");
    __builtin_amdgcn_s_barrier();
    compute((NK - 1) & 1);

    const int hbase = basep[e];
    #pragma unroll
    for (int i = 0; i < 4; i++) {
        #pragma unroll
        for (int r = 0; r < 4; r++) {
            int rl = wy * 64 + i * 16 + quad * 4 + r;   // C/D: row=(lane>>4)*4+reg
            int gr = row0 + rl;
            if (gr < cnt) {
                _Float16* hrow = h + (size_t)(hbase + gr) * FDIM;
                #pragma unroll
                for (int j = 0; j < 4; j++) {
                    int c = col0 + wx * 64 + j * 16 + m_lane;   // C/D: col=lane&15
                    float v = acc[i][j][r] + bias1[e * FDIM + c];
                    hrow[c] = (_Float16)gelu_exact(v);
                }
            }
        }
    }
}

// ================= GEMM2: out += gate_w * (h @ w2[e] + b2[e]) =================
// 128x64 tile (2x grid vs 128x128), BK=32, pipelined double-buffer.
// Waves 2x2: wave tile 64 rows x 32 cols (4x2 mfma). 3 DMAs/wave/iter.
__global__ __launch_bounds__(256) void mm2_kernel(const _Float16* __restrict__ h,
                                                  const _Float16* __restrict__ w2t,
                                                  const float* __restrict__ bias2,
                                                  const int* __restrict__ tok_list,
                                                  const float* __restrict__ wt_list,
                                                  const int* __restrict__ count,
                                                  const int* __restrict__ basep,
                                                  float* __restrict__ out) {
    const int e    = blockIdx.z;
    const int cnt  = count[e];
    const int row0 = blockIdx.y * 128;
    if (row0 >= cnt) return;
    const int col0 = blockIdx.x * 64;
    const int t    = threadIdx.x;
    const int lane = t & 63;
    const int wv   = t >> 6;
    const int wy   = wv >> 1, wx = wv & 1;
    const int m_lane = lane & 15, quad = lane >> 4;

    __shared__ __align__(16) _Float16 As[2][4096];   // 8 blocks x 512
    __shared__ __align__(16) _Float16 Bs[2][2048];   // 4 blocks x 512

    const int hbase = basep[e];
    const int b0 = wv * 2, b1 = b0 + 1;
    int ra0 = row0 + b0 * 16 + m_lane; if (ra0 > cnt - 1) ra0 = cnt - 1;
    int ra1 = row0 + b1 * 16 + m_lane; if (ra1 > cnt - 1) ra1 = cnt - 1;
    const _Float16* pa0 = h + (size_t)(hbase + ra0) * FDIM + quad * 8;
    const _Float16* pa1 = h + (size_t)(hbase + ra1) * FDIM + quad * 8;
    const _Float16* pb  = w2t + (size_t)e * DIM * FDIM
                        + (size_t)(col0 + wv * 16 + m_lane) * FDIM + quad * 8;

    f32x4 acc[4][2];
    #pragma unroll
    for (int i = 0; i < 4; i++)
        #pragma unroll
        for (int j = 0; j < 2; j++)
            acc[i][j] = (f32x4){0.f, 0.f, 0.f, 0.f};

    auto compute = [&](int cur) {
        f16x8 af[4], bf[2];
        #pragma unroll
        for (int i = 0; i < 4; i++)
            af[i] = *(const f16x8*)&As[cur][(wy * 4 + i) * 512 + lane * 8];
        #pragma unroll
        for (int j = 0; j < 2; j++)
            bf[j] = *(const f16x8*)&Bs[cur][(wx * 2 + j) * 512 + lane * 8];
        #pragma unroll
        for (int i = 0; i < 4; i++)
            #pragma unroll
            for (int j = 0; j < 2; j++)
                acc[i][j] = __builtin_amdgcn_mfma_f32_16x16x32_f16(af[i], bf[j], acc[i][j], 0, 0, 0);
    };

    const int NK = FDIM / 32;   // 96
    gl_lds16(pa0, &As[0][b0 * 512]);
    gl_lds16(pa1, &As[0][b1 * 512]);
    gl_lds16(pb,  &Bs[0][wv * 512]);

    for (int k = 0; k < NK - 1; k++) {
        const int cur = k & 1, nxt = cur ^ 1;
        const int off = (k + 1) * 32;
        gl_lds16(pa0 + off, &As[nxt][b0 * 512]);
        gl_lds16(pa1 + off, &As[nxt][b1 * 512]);
        gl_lds16(pb  + off, &Bs[nxt][wv * 512]);
        asm volatile("s_waitcnt vmcnt(3)" ::: "memory");
        __builtin_amdgcn_s_barrier();
        compute(cur);
        __builtin_amdgcn_s_barrier();
    }
    asm volatile("s_waitcnt vmcnt(0)" ::: "memory");
    __builtin_amdgcn_s_barrier();
    compute((NK - 1) & 1);

    #pragma unroll
    for (int i = 0; i < 4; i++) {
        #pragma unroll
        for (int r = 0; r < 4; r++) {
            int rl = wy * 64 + i * 16 + quad * 4 + r;
            int gr = row0 + rl;
            if (gr < cnt) {
                int tok   = tok_list[e * N_TOK + gr];
                float wgt = wt_list[e * N_TOK + gr];
                float* orow = out + (size_t)tok * DIM;
                #pragma unroll
                for (int j = 0; j < 2; j++) {
                    int c = col0 + wx * 32 + j * 16 + m_lane;
                    float v = acc[i][j][r] + bias2[e * DIM + c];
                    atomicAdd(&orow[c], wgt * v);
                }
            }
        }
    }
}

extern "C" void kernel_launch(void* const* d_in, const int* in_sizes, int n_in,
                              void* d_out, int out_size, void* d_ws, size_t ws_size,
                              hipStream_t stream) {
    const float* x  = (const float*)d_in[0];
    const float* gw = (const float*)d_in[1];
    const float* gb = (const float*)d_in[2];
    const float* w1 = (const float*)d_in[3];
    const float* b1 = (const float*)d_in[4];
    const float* w2 = (const float*)d_in[5];
    const float* b2 = (const float*)d_in[6];
    float* out = (float*)d_out;

    char* ws = (char*)d_ws;
    _Float16* xh   = (_Float16*)ws;                                    // 4096*768
    _Float16* w1t  = xh  + (size_t)N_TOK * DIM;                        // [E][F][D]
    _Float16* w2t  = w1t + (size_t)NEXP * FDIM * DIM;                  // [E][D][F]
    _Float16* hbuf = w2t + (size_t)NEXP * DIM * FDIM;                  // [2N][F] compact slots
    int*   tok_list = (int*)(hbuf + (size_t)2 * N_TOK * FDIM);         // [E][N]
    float* wt_list  = (float*)(tok_list + NEXP * N_TOK);               // [E][N]
    int*   count    = (int*)(wt_list + NEXP * N_TOK);                  // [E]
    int*   basep    = count + 8;                                       // [E]

    hipMemsetAsync(count, 0, 64, stream);
    hipMemsetAsync(out, 0, (size_t)out_size * sizeof(float), stream);

    cast_x_kernel<<<dim3(N_TOK * DIM / 4 / 256), 256, 0, stream>>>(x, xh);
    transpose_cast_kernel<<<dim3(FDIM / 64, DIM / 64, NEXP), 256, 0, stream>>>(w1, w1t, DIM, FDIM);
    transpose_cast_kernel<<<dim3(DIM / 64, FDIM / 64, NEXP), 256, 0, stream>>>(w2, w2t, FDIM, DIM);
    gate_kernel<<<dim3(N_TOK / 4), 256, 0, stream>>>(x, gw, gb, tok_list, wt_list, count);
    scan_kernel<<<1, 64, 0, stream>>>(count, basep);
    mm1_kernel<<<dim3(FDIM / 128, N_TOK / 128, NEXP), 256, 0, stream>>>(
        xh, w1t, b1, tok_list, count, basep, hbuf);
    mm2_kernel<<<dim3(DIM / 64, N_TOK / 128, NEXP), 256, 0, stream>>>(
        hbuf, w2t, b2, tok_list, wt_list, count, basep, out);
}

// Round 4
// 540.901 us; speedup vs baseline: 1.1614x; 1.1614x over previous
//
#include <hip/hip_runtime.h>
#include <hip/hip_bf16.h>

// MoE layer, routed top-2. f16 MFMA (fp32 accumulate), fp64 gating.
// Round 4: back to compiler-friendly VGPR staging (register prefetch of tile
// k+1 during compute of tile k), fragment-order conflict-free LDS, LDS-
// transposed coalesced epilogues (f16x8 stores), tanh-GELU, no atomics
// (mm2 -> per-slot y buffer + gather combine kernel).

#define N_TOK 4096
#define DIM   768
#define FDIM  3072
#define NEXP  8

typedef __attribute__((ext_vector_type(8))) _Float16 f16x8;
typedef __attribute__((ext_vector_type(4))) _Float16 f16x4;
typedef __attribute__((ext_vector_type(4))) float     f32x4;

__device__ __forceinline__ float gelu_fast(float v) {
    // tanh-form GELU; |err vs exact-erf| < ~2e-3 absolute
    float u = 0.7978845608f * v * (1.0f + 0.044715f * v * v);
    float t = 1.0f - 2.0f / (1.0f + __expf(2.0f * u));
    return 0.5f * v * (1.0f + t);
}

// ---------------- cast x (fp32 -> f16), vectorized ----------------
__global__ __launch_bounds__(256) void cast_x_kernel(const float* __restrict__ x,
                                                     _Float16* __restrict__ xh) {
    int i = blockIdx.x * 256 + threadIdx.x;
    float4 v = ((const float4*)x)[i];
    f16x4 o;
    o[0] = (_Float16)v.x; o[1] = (_Float16)v.y;
    o[2] = (_Float16)v.z; o[3] = (_Float16)v.w;
    ((f16x4*)xh)[i] = o;
}

// ---------------- transpose + cast: fp32 [E][R][C] -> f16 [E][C][R] ----------------
__global__ __launch_bounds__(256) void transpose_cast_kernel(const float* __restrict__ in,
                                                             _Float16* __restrict__ out,
                                                             int R, int C) {
    const int e  = blockIdx.z;
    const size_t eoff = (size_t)e * R * C;
    const int c0 = blockIdx.x * 64;
    const int r0 = blockIdx.y * 64;
    __shared__ _Float16 tile[64][66];
    const int t = threadIdx.x;
    #pragma unroll
    for (int it = 0; it < 4; it++) {
        int lin = it * 256 + t;
        int r  = lin >> 4;
        int c4 = lin & 15;
        float4 v = *(const float4*)&in[eoff + (size_t)(r0 + r) * C + c0 + c4 * 4];
        tile[r][c4 * 4 + 0] = (_Float16)v.x;
        tile[r][c4 * 4 + 1] = (_Float16)v.y;
        tile[r][c4 * 4 + 2] = (_Float16)v.z;
        tile[r][c4 * 4 + 3] = (_Float16)v.w;
    }
    __syncthreads();
    #pragma unroll
    for (int it = 0; it < 4; it++) {
        int lin = it * 256 + t;
        int c  = lin >> 4;
        int r4 = lin & 15;
        f16x4 o;
        #pragma unroll
        for (int j = 0; j < 4; j++) o[j] = tile[r4 * 4 + j][c];
        *(f16x4*)&out[eoff + (size_t)(c0 + c) * R + r0 + r4 * 4] = o;
    }
}

// ---------------- gating: fp64 logits, softmax, top-2, lists + inverse map ----------------
__global__ __launch_bounds__(256) void gate_kernel(const float* __restrict__ x,
                                                   const float* __restrict__ gw,
                                                   const float* __restrict__ gb,
                                                   int* __restrict__ tok_list,
                                                   float* __restrict__ wt_list,
                                                   int* __restrict__ count,
                                                   int2* __restrict__ inv) {
    const int gtid = blockIdx.x * 256 + threadIdx.x;
    const int n    = gtid >> 6;
    const int lane = threadIdx.x & 63;
    if (n >= N_TOK) return;
    double part[NEXP];
    #pragma unroll
    for (int e = 0; e < NEXP; e++) part[e] = 0.0;
    for (int d = lane; d < DIM; d += 64) {
        float xv = x[n * DIM + d];
        const float* g = &gw[d * NEXP];
        #pragma unroll
        for (int e = 0; e < NEXP; e++) part[e] += (double)xv * (double)g[e];
    }
    #pragma unroll
    for (int e = 0; e < NEXP; e++) {
        double v = part[e];
        #pragma unroll
        for (int off = 32; off > 0; off >>= 1) v += __shfl_xor(v, off);
        part[e] = v + (double)gb[e];
    }
    if (lane == 0) {
        double mx = part[0];
        #pragma unroll
        for (int e = 1; e < NEXP; e++) mx = fmax(mx, part[e]);
        double ex[NEXP]; double s = 0.0;
        #pragma unroll
        for (int e = 0; e < NEXP; e++) { ex[e] = exp(part[e] - mx); s += ex[e]; }
        int i0 = 0;
        #pragma unroll
        for (int e = 1; e < NEXP; e++) if (ex[e] > ex[i0]) i0 = e;
        int i1 = (i0 == 0) ? 1 : 0;
        #pragma unroll
        for (int e = 0; e < NEXP; e++) if (e != i0 && ex[e] > ex[i1]) i1 = e;
        float g0 = (float)(ex[i0] / s), g1 = (float)(ex[i1] / s);
        float dn = g0 + g1 + 1e-9f;
        float w0 = g0 / dn, w1 = g1 / dn;
        int s0 = atomicAdd(&count[i0], 1);
        tok_list[i0 * N_TOK + s0] = n;  wt_list[i0 * N_TOK + s0] = w0;
        int s1 = atomicAdd(&count[i1], 1);
        tok_list[i1 * N_TOK + s1] = n;  wt_list[i1 * N_TOK + s1] = w1;
        inv[n] = make_int2((i0 << 16) | s0, (i1 << 16) | s1);
    }
}

// ---------------- tiny prefix scan over 8 expert counts ----------------
__global__ void scan_kernel(const int* __restrict__ count, int* __restrict__ basep) {
    if (threadIdx.x == 0) {
        int s = 0;
        for (int e = 0; e < NEXP; e++) { basep[e] = s; s += count[e]; }
    }
}

// ================= GEMM1: h = gelu(x_gathered @ w1[e] + b1[e]) =================
// 128x128 tile, BK=32, 4 waves (2x2), 4x4 mfma 16x16x32. Fragment-order LDS
// [block(16rows)][quad][m][8]: staging ds_write_b128 and fragment ds_read_b128
// are lane-contiguous -> 0 bank conflicts. Register prefetch of tile k+1
// issued before compute of tile k (compiler schedules the waitcnt late).
// Epilogue: bias+gelu -> LDS ctile (pitch 132) -> coalesced f16x8 stores.
__global__ __launch_bounds__(256) void mm1_kernel(const _Float16* __restrict__ xh,
                                                  const _Float16* __restrict__ w1t,
                                                  const float* __restrict__ bias1,
                                                  const int* __restrict__ tok_list,
                                                  const int* __restrict__ count,
                                                  const int* __restrict__ basep,
                                                  _Float16* __restrict__ h) {
    const int e    = blockIdx.z;
    const int cnt  = count[e];
    const int row0 = blockIdx.y * 128;
    if (row0 >= cnt) return;
    const int col0 = blockIdx.x * 128;
    const int t    = threadIdx.x;
    const int lane = t & 63;
    const int wv   = t >> 6;
    const int wy   = wv >> 1, wx = wv & 1;
    const int m_lane = lane & 15, quad = lane >> 4;

    __shared__ __align__(16) _Float16 smem[128 * 132];   // 33792 B; aliases staging+ctile
    _Float16* As = smem;            // 4096
    _Float16* Bs = smem + 4096;     // 4096

    const int b0 = wv * 2, b1 = b0 + 1;
    int ra0 = row0 + b0 * 16 + m_lane; if (ra0 > cnt - 1) ra0 = cnt - 1;
    int ra1 = row0 + b1 * 16 + m_lane; if (ra1 > cnt - 1) ra1 = cnt - 1;
    const int tokA0 = tok_list[e * N_TOK + ra0];
    const int tokA1 = tok_list[e * N_TOK + ra1];
    const _Float16* pa0 = xh + (size_t)tokA0 * DIM + quad * 8;
    const _Float16* pa1 = xh + (size_t)tokA1 * DIM + quad * 8;
    const _Float16* pb0 = w1t + (size_t)e * FDIM * DIM
                        + (size_t)(col0 + b0 * 16 + m_lane) * DIM + quad * 8;
    const _Float16* pb1 = pb0 + (size_t)16 * DIM;

    f32x4 acc[4][4];
    #pragma unroll
    for (int i = 0; i < 4; i++)
        #pragma unroll
        for (int j = 0; j < 4; j++)
            acc[i][j] = (f32x4){0.f, 0.f, 0.f, 0.f};

    const int NK = DIM / 32;   // 24
    uint4 rA0 = *(const uint4*)pa0;
    uint4 rA1 = *(const uint4*)pa1;
    uint4 rB0 = *(const uint4*)pb0;
    uint4 rB1 = *(const uint4*)pb1;

    for (int k = 0; k < NK; k++) {
        __syncthreads();                       // prior tile's LDS reads done
        *(uint4*)&As[b0 * 512 + lane * 8] = rA0;
        *(uint4*)&As[b1 * 512 + lane * 8] = rA1;
        *(uint4*)&Bs[b0 * 512 + lane * 8] = rB0;
        *(uint4*)&Bs[b1 * 512 + lane * 8] = rB1;
        if (k + 1 < NK) {                      // prefetch next tile into regs
            const int off = (k + 1) * 32;
            rA0 = *(const uint4*)(pa0 + off);
            rA1 = *(const uint4*)(pa1 + off);
            rB0 = *(const uint4*)(pb0 + off);
            rB1 = *(const uint4*)(pb1 + off);
        }
        __syncthreads();
        f16x8 af[4], bf[4];
        #pragma unroll
        for (int i = 0; i < 4; i++)
            af[i] = *(const f16x8*)&As[(wy * 4 + i) * 512 + lane * 8];
        #pragma unroll
        for (int j = 0; j < 4; j++)
            bf[j] = *(const f16x8*)&Bs[(wx * 4 + j) * 512 + lane * 8];
        #pragma unroll
        for (int i = 0; i < 4; i++)
            #pragma unroll
            for (int j = 0; j < 4; j++)
                acc[i][j] = __builtin_amdgcn_mfma_f32_16x16x32_f16(af[i], bf[j], acc[i][j], 0, 0, 0);
    }

    // -------- epilogue: regs -> LDS ctile -> coalesced f16x8 stores --------
    __syncthreads();                           // done reading As/Bs
    float bj[4];
    #pragma unroll
    for (int j = 0; j < 4; j++)
        bj[j] = bias1[e * FDIM + col0 + wx * 64 + j * 16 + m_lane];
    #pragma unroll
    for (int i = 0; i < 4; i++)
        #pragma unroll
        for (int j = 0; j < 4; j++)
            #pragma unroll
            for (int r = 0; r < 4; r++) {
                int rr = wy * 64 + i * 16 + quad * 4 + r;
                int cc = wx * 64 + j * 16 + m_lane;
                smem[rr * 132 + cc] = (_Float16)gelu_fast(acc[i][j][r] + bj[j]);
            }
    __syncthreads();
    const int hbase = basep[e];
    #pragma unroll
    for (int s = 0; s < 8; s++) {
        int chunk = s * 256 + t;               // 2048 chunks of 8
        int row = chunk >> 4;
        int col = (chunk & 15) * 8;
        if (row0 + row < cnt) {
            f16x4 lo = *(const f16x4*)&smem[row * 132 + col];
            f16x4 hi = *(const f16x4*)&smem[row * 132 + col + 4];
            f16x8 v;
            v[0]=lo[0]; v[1]=lo[1]; v[2]=lo[2]; v[3]=lo[3];
            v[4]=hi[0]; v[5]=hi[1]; v[6]=hi[2]; v[7]=hi[3];
            *(f16x8*)&h[(size_t)(hbase + row0 + row) * FDIM + col0 + col] = v;
        }
    }
}

// ================= GEMM2: y[slot] = wgt * (h @ w2[e] + b2[e]) (f16) =================
__global__ __launch_bounds__(256) void mm2_kernel(const _Float16* __restrict__ h,
                                                  const _Float16* __restrict__ w2t,
                                                  const float* __restrict__ bias2,
                                                  const float* __restrict__ wt_list,
                                                  const int* __restrict__ count,
                                                  const int* __restrict__ basep,
                                                  _Float16* __restrict__ y) {
    const int e    = blockIdx.z;
    const int cnt  = count[e];
    const int row0 = blockIdx.y * 128;
    if (row0 >= cnt) return;
    const int col0 = blockIdx.x * 128;
    const int t    = threadIdx.x;
    const int lane = t & 63;
    const int wv   = t >> 6;
    const int wy   = wv >> 1, wx = wv & 1;
    const int m_lane = lane & 15, quad = lane >> 4;

    __shared__ __align__(16) _Float16 smem[128 * 132];
    _Float16* As = smem;
    _Float16* Bs = smem + 4096;

    const int hbase = basep[e];
    const int b0 = wv * 2, b1 = b0 + 1;
    int ra0 = row0 + b0 * 16 + m_lane; if (ra0 > cnt - 1) ra0 = cnt - 1;
    int ra1 = row0 + b1 * 16 + m_lane; if (ra1 > cnt - 1) ra1 = cnt - 1;
    const _Float16* pa0 = h + (size_t)(hbase + ra0) * FDIM + quad * 8;
    const _Float16* pa1 = h + (size_t)(hbase + ra1) * FDIM + quad * 8;
    const _Float16* pb0 = w2t + (size_t)e * DIM * FDIM
                        + (size_t)(col0 + b0 * 16 + m_lane) * FDIM + quad * 8;
    const _Float16* pb1 = pb0 + (size_t)16 * FDIM;

    f32x4 acc[4][4];
    #pragma unroll
    for (int i = 0; i < 4; i++)
        #pragma unroll
        for (int j = 0; j < 4; j++)
            acc[i][j] = (f32x4){0.f, 0.f, 0.f, 0.f};

    const int NK = FDIM / 32;   // 96
    uint4 rA0 = *(const uint4*)pa0;
    uint4 rA1 = *(const uint4*)pa1;
    uint4 rB0 = *(const uint4*)pb0;
    uint4 rB1 = *(const uint4*)pb1;

    for (int k = 0; k < NK; k++) {
        __syncthreads();
        *(uint4*)&As[b0 * 512 + lane * 8] = rA0;
        *(uint4*)&As[b1 * 512 + lane * 8] = rA1;
        *(uint4*)&Bs[b0 * 512 + lane * 8] = rB0;
        *(uint4*)&Bs[b1 * 512 + lane * 8] = rB1;
        if (k + 1 < NK) {
            const int off = (k + 1) * 32;
            rA0 = *(const uint4*)(pa0 + off);
            rA1 = *(const uint4*)(pa1 + off);
            rB0 = *(const uint4*)(pb0 + off);
            rB1 = *(const uint4*)(pb1 + off);
        }
        __syncthreads();
        f16x8 af[4], bf[4];
        #pragma unroll
        for (int i = 0; i < 4; i++)
            af[i] = *(const f16x8*)&As[(wy * 4 + i) * 512 + lane * 8];
        #pragma unroll
        for (int j = 0; j < 4; j++)
            bf[j] = *(const f16x8*)&Bs[(wx * 4 + j) * 512 + lane * 8];
        #pragma unroll
        for (int i = 0; i < 4; i++)
            #pragma unroll
            for (int j = 0; j < 4; j++)
                acc[i][j] = __builtin_amdgcn_mfma_f32_16x16x32_f16(af[i], bf[j], acc[i][j], 0, 0, 0);
    }

    // -------- epilogue: weighted bias add -> LDS ctile -> f16x8 stores to y --------
    __syncthreads();
    float bj[4];
    #pragma unroll
    for (int j = 0; j < 4; j++)
        bj[j] = bias2[e * DIM + col0 + wx * 64 + j * 16 + m_lane];
    #pragma unroll
    for (int i = 0; i < 4; i++) {
        #pragma unroll
        for (int r = 0; r < 4; r++) {
            int rr = wy * 64 + i * 16 + quad * 4 + r;
            float wgt = wt_list[e * N_TOK + row0 + rr];   // in-bounds; masked at store
            #pragma unroll
            for (int j = 0; j < 4; j++) {
                int cc = wx * 64 + j * 16 + m_lane;
                smem[rr * 132 + cc] = (_Float16)(wgt * (acc[i][j][r] + bj[j]));
            }
        }
    }
    __syncthreads();
    #pragma unroll
    for (int s = 0; s < 8; s++) {
        int chunk = s * 256 + t;
        int row = chunk >> 4;
        int col = (chunk & 15) * 8;
        if (row0 + row < cnt) {
            f16x4 lo = *(const f16x4*)&smem[row * 132 + col];
            f16x4 hi = *(const f16x4*)&smem[row * 132 + col + 4];
            f16x8 v;
            v[0]=lo[0]; v[1]=lo[1]; v[2]=lo[2]; v[3]=lo[3];
            v[4]=hi[0]; v[5]=hi[1]; v[6]=hi[2]; v[7]=hi[3];
            *(f16x8*)&y[(size_t)(hbase + row0 + row) * DIM + col0 + col] = v;
        }
    }
}

// ================= combine: out[n] = y[slot0(n)] + y[slot1(n)] =================
__global__ __launch_bounds__(192) void combine_kernel(const _Float16* __restrict__ y,
                                                      const int2* __restrict__ inv,
                                                      const int* __restrict__ basep,
                                                      float* __restrict__ out) {
    const int n = blockIdx.x * 2 + (threadIdx.x >= 96);
    const int c = (threadIdx.x % 96) * 8;
    int2 iv = inv[n];
    int s0 = basep[(iv.x >> 16) & 0x7] + (iv.x & 0xffff);
    int s1 = basep[(iv.y >> 16) & 0x7] + (iv.y & 0xffff);
    f16x8 a = *(const f16x8*)&y[(size_t)s0 * DIM + c];
    f16x8 b = *(const f16x8*)&y[(size_t)s1 * DIM + c];
    float4 o0, o1;
    o0.x = (float)a[0] + (float)b[0];  o0.y = (float)a[1] + (float)b[1];
    o0.z = (float)a[2] + (float)b[2];  o0.w = (float)a[3] + (float)b[3];
    o1.x = (float)a[4] + (float)b[4];  o1.y = (float)a[5] + (float)b[5];
    o1.z = (float)a[6] + (float)b[6];  o1.w = (float)a[7] + (float)b[7];
    *(float4*)&out[(size_t)n * DIM + c]     = o0;
    *(float4*)&out[(size_t)n * DIM + c + 4] = o1;
}

extern "C" void kernel_launch(void* const* d_in, const int* in_sizes, int n_in,
                              void* d_out, int out_size, void* d_ws, size_t ws_size,
                              hipStream_t stream) {
    const float* x  = (const float*)d_in[0];
    const float* gw = (const float*)d_in[1];
    const float* gb = (const float*)d_in[2];
    const float* w1 = (const float*)d_in[3];
    const float* b1 = (const float*)d_in[4];
    const float* w2 = (const float*)d_in[5];
    const float* b2 = (const float*)d_in[6];
    float* out = (float*)d_out;

    char* ws = (char*)d_ws;
    _Float16* xh   = (_Float16*)ws;                                    // 4096*768
    _Float16* w1t  = xh  + (size_t)N_TOK * DIM;                        // [E][F][D]
    _Float16* w2t  = w1t + (size_t)NEXP * FDIM * DIM;                  // [E][D][F]
    _Float16* hbuf = w2t + (size_t)NEXP * DIM * FDIM;                  // [2N][F] compact slots
    int*   tok_list = (int*)(hbuf + (size_t)2 * N_TOK * FDIM);         // [E][N]
    float* wt_list  = (float*)(tok_list + NEXP * N_TOK);               // [E][N]
    int2*  inv      = (int2*)(wt_list + NEXP * N_TOK);                 // [N]
    int*   count    = (int*)(inv + N_TOK);                             // [E]
    int*   basep    = count + 8;                                       // [E]
    _Float16* ybuf  = w1t;   // w1t dead after mm1; y = [2N][D] (12.6 MB <= 37.7 MB)

    hipMemsetAsync(count, 0, 64, stream);

    cast_x_kernel<<<dim3(N_TOK * DIM / 4 / 256), 256, 0, stream>>>(x, xh);
    transpose_cast_kernel<<<dim3(FDIM / 64, DIM / 64, NEXP), 256, 0, stream>>>(w1, w1t, DIM, FDIM);
    transpose_cast_kernel<<<dim3(DIM / 64, FDIM / 64, NEXP), 256, 0, stream>>>(w2, w2t, FDIM, DIM);
    gate_kernel<<<dim3(N_TOK / 4), 256, 0, stream>>>(x, gw, gb, tok_list, wt_list, count, inv);
    scan_kernel<<<1, 64, 0, stream>>>(count, basep);
    mm1_kernel<<<dim3(FDIM / 128, N_TOK / 128, NEXP), 256, 0, stream>>>(
        xh, w1t, b1, tok_list, count, basep, hbuf);
    mm2_kernel<<<dim3(DIM / 128, N_TOK / 128, NEXP), 256, 0, stream>>>(
        hbuf, w2t, b2, wt_list, count, basep, ybuf);
    combine_kernel<<<dim3(N_TOK / 2), 192, 0, stream>>>(ybuf, inv, basep, out);
}